// Round 3
// baseline (1432.063 us; speedup 1.0000x reference)
//
#include <hip/hip_runtime.h>
#include <math.h>
#include <cstddef>
#include <cstdint>

#define B_ 8
#define S_ 4096
#define D_ 256

typedef __attribute__((ext_vector_type(8))) short short8v;   // 8 bf16 (4 VGPR)
typedef __attribute__((ext_vector_type(4))) short short4v;   // 4 bf16 (8 B)
typedef __attribute__((ext_vector_type(4))) float float4v;   // MFMA C/D

// float -> bf16 (RNE) and back, on bit patterns
__device__ __forceinline__ unsigned short f2bf(float f) {
  unsigned u = __float_as_uint(f);
  return (unsigned short)((u + 0x7FFF + ((u >> 16) & 1)) >> 16);
}
__device__ __forceinline__ float bf2f(unsigned short h) {
  return __uint_as_float((unsigned)h << 16);
}

// ---------------------------------------------------------------------------
// fp32 GEMM (used for Wo): C[M,256] = A @ W + bias, natural layout.
// ---------------------------------------------------------------------------
__global__ __launch_bounds__(256, 2) void gemm_bias_kernel(
    const float* __restrict__ A, const float* __restrict__ W,
    const float* __restrict__ bias, float* __restrict__ C) {
  __shared__ __align__(16) float sA[32 * 68];
  __shared__ __align__(16) float sW[32 * 260];
  const int t  = threadIdx.x;
  const int tx = t & 31;
  const int ty = t >> 5;
  const size_t m0 = (size_t)blockIdx.x * 64;

  float acc[8][8] = {};

  for (int kc = 0; kc < 8; ++kc) {
    const int k0 = kc << 5;
    __syncthreads();
#pragma unroll
    for (int l = 0; l < 2; ++l) {
      const int idx = t + (l << 8);
      const int r = idx >> 3, cf = (idx & 7) << 2;
      const float4 a4 = *(const float4*)(A + (m0 + r) * 256 + k0 + cf);
      sA[(cf + 0) * 68 + r] = a4.x;
      sA[(cf + 1) * 68 + r] = a4.y;
      sA[(cf + 2) * 68 + r] = a4.z;
      sA[(cf + 3) * 68 + r] = a4.w;
    }
#pragma unroll
    for (int l = 0; l < 8; ++l) {
      const int idx = t + (l << 8);
      const int kr = idx >> 6, nc = (idx & 63) << 2;
      *(float4*)&sW[kr * 260 + nc] =
          *(const float4*)(W + (size_t)(k0 + kr) * 256 + nc);
    }
    __syncthreads();
#pragma unroll
    for (int kk = 0; kk < 32; ++kk) {
      const float4 a0 = *(const float4*)&sA[kk * 68 + (ty << 3)];
      const float4 a1 = *(const float4*)&sA[kk * 68 + (ty << 3) + 4];
      const float4 b0 = *(const float4*)&sW[kk * 260 + (tx << 2)];
      const float4 b1 = *(const float4*)&sW[kk * 260 + 128 + (tx << 2)];
      const float av[8] = {a0.x, a0.y, a0.z, a0.w, a1.x, a1.y, a1.z, a1.w};
      const float bv[8] = {b0.x, b0.y, b0.z, b0.w, b1.x, b1.y, b1.z, b1.w};
#pragma unroll
      for (int i = 0; i < 8; ++i)
#pragma unroll
        for (int c = 0; c < 8; ++c) acc[i][c] += av[i] * bv[c];
    }
  }

  const float4 bb0 = *(const float4*)(bias + (tx << 2));
  const float4 bb1 = *(const float4*)(bias + 128 + (tx << 2));
#pragma unroll
  for (int i = 0; i < 8; ++i) {
    float4 o0, o1;
    o0.x = acc[i][0] + bb0.x; o0.y = acc[i][1] + bb0.y;
    o0.z = acc[i][2] + bb0.z; o0.w = acc[i][3] + bb0.w;
    o1.x = acc[i][4] + bb1.x; o1.y = acc[i][5] + bb1.y;
    o1.z = acc[i][6] + bb1.z; o1.w = acc[i][7] + bb1.w;
    float* cp = C + (m0 + (ty << 3) + i) * 256;
    *(float4*)(cp + (tx << 2)) = o0;
    *(float4*)(cp + 128 + (tx << 2)) = o1;
  }
}

// ---------------------------------------------------------------------------
// Projection GEMM -> split-bf16 NATURAL output [b][s][d]: yh + yl (hi/lo).
// scale folded in before the split (Q uses 1/16, K uses 1).
// ---------------------------------------------------------------------------
__global__ __launch_bounds__(256, 2) void proj_split_nat_kernel(
    const float* __restrict__ A, const float* __restrict__ W,
    const float* __restrict__ bias, short* __restrict__ outh,
    short* __restrict__ outl, float scale) {
  __shared__ __align__(16) float sA[32 * 68];
  __shared__ __align__(16) float sW[32 * 260];
  const int t  = threadIdx.x;
  const int tx = t & 31;
  const int ty = t >> 5;
  const size_t m0 = (size_t)blockIdx.x * 64;

  float acc[8][8] = {};

  for (int kc = 0; kc < 8; ++kc) {
    const int k0 = kc << 5;
    __syncthreads();
#pragma unroll
    for (int l = 0; l < 2; ++l) {
      const int idx = t + (l << 8);
      const int r = idx >> 3, cf = (idx & 7) << 2;
      const float4 a4 = *(const float4*)(A + (m0 + r) * 256 + k0 + cf);
      sA[(cf + 0) * 68 + r] = a4.x;
      sA[(cf + 1) * 68 + r] = a4.y;
      sA[(cf + 2) * 68 + r] = a4.z;
      sA[(cf + 3) * 68 + r] = a4.w;
    }
#pragma unroll
    for (int l = 0; l < 8; ++l) {
      const int idx = t + (l << 8);
      const int kr = idx >> 6, nc = (idx & 63) << 2;
      *(float4*)&sW[kr * 260 + nc] =
          *(const float4*)(W + (size_t)(k0 + kr) * 256 + nc);
    }
    __syncthreads();
#pragma unroll
    for (int kk = 0; kk < 32; ++kk) {
      const float4 a0 = *(const float4*)&sA[kk * 68 + (ty << 3)];
      const float4 a1 = *(const float4*)&sA[kk * 68 + (ty << 3) + 4];
      const float4 b0 = *(const float4*)&sW[kk * 260 + (tx << 2)];
      const float4 b1 = *(const float4*)&sW[kk * 260 + 128 + (tx << 2)];
      const float av[8] = {a0.x, a0.y, a0.z, a0.w, a1.x, a1.y, a1.z, a1.w};
      const float bv[8] = {b0.x, b0.y, b0.z, b0.w, b1.x, b1.y, b1.z, b1.w};
#pragma unroll
      for (int i = 0; i < 8; ++i)
#pragma unroll
        for (int c = 0; c < 8; ++c) acc[i][c] += av[i] * bv[c];
    }
  }

  const float4 bb0 = *(const float4*)(bias + (tx << 2));
  const float4 bb1 = *(const float4*)(bias + 128 + (tx << 2));
  const float bb0v[4] = {bb0.x, bb0.y, bb0.z, bb0.w};
  const float bb1v[4] = {bb1.x, bb1.y, bb1.z, bb1.w};
#pragma unroll
  for (int i = 0; i < 8; ++i) {
    const size_t ro = (m0 + (ty << 3) + i) * 256;
    short4v h0, l0, h1, l1;
#pragma unroll
    for (int c = 0; c < 4; ++c) {
      const float y0 = (acc[i][c] + bb0v[c]) * scale;
      const unsigned short hh0 = f2bf(y0);
      h0[c] = (short)hh0; l0[c] = (short)f2bf(y0 - bf2f(hh0));
      const float y1 = (acc[i][4 + c] + bb1v[c]) * scale;
      const unsigned short hh1 = f2bf(y1);
      h1[c] = (short)hh1; l1[c] = (short)f2bf(y1 - bf2f(hh1));
    }
    *(short4v*)(outh + ro + (tx << 2)) = h0;
    *(short4v*)(outl + ro + (tx << 2)) = l0;
    *(short4v*)(outh + ro + 128 + (tx << 2)) = h1;
    *(short4v*)(outl + ro + 128 + (tx << 2)) = l1;
  }
}

// ---------------------------------------------------------------------------
// V projection -> split-bf16 TRANSPOSED output [b][d][s]: vth + vtl.
// ---------------------------------------------------------------------------
__global__ __launch_bounds__(256, 2) void proj_split_t_kernel(
    const float* __restrict__ A, const float* __restrict__ W,
    const float* __restrict__ bias, short* __restrict__ vth,
    short* __restrict__ vtl) {
  __shared__ __align__(16) float sA[32 * 68];
  __shared__ __align__(16) float sW[32 * 260];
  const int t  = threadIdx.x;
  const int tx = t & 31;
  const int ty = t >> 5;
  const size_t m0 = (size_t)blockIdx.x * 64;

  float acc[8][8] = {};

  for (int kc = 0; kc < 8; ++kc) {
    const int k0 = kc << 5;
    __syncthreads();
#pragma unroll
    for (int l = 0; l < 2; ++l) {
      const int idx = t + (l << 8);
      const int r = idx >> 3, cf = (idx & 7) << 2;
      const float4 a4 = *(const float4*)(A + (m0 + r) * 256 + k0 + cf);
      sA[(cf + 0) * 68 + r] = a4.x;
      sA[(cf + 1) * 68 + r] = a4.y;
      sA[(cf + 2) * 68 + r] = a4.z;
      sA[(cf + 3) * 68 + r] = a4.w;
    }
#pragma unroll
    for (int l = 0; l < 8; ++l) {
      const int idx = t + (l << 8);
      const int kr = idx >> 6, nc = (idx & 63) << 2;
      *(float4*)&sW[kr * 260 + nc] =
          *(const float4*)(W + (size_t)(k0 + kr) * 256 + nc);
    }
    __syncthreads();
#pragma unroll
    for (int kk = 0; kk < 32; ++kk) {
      const float4 a0 = *(const float4*)&sA[kk * 68 + (ty << 3)];
      const float4 a1 = *(const float4*)&sA[kk * 68 + (ty << 3) + 4];
      const float4 b0 = *(const float4*)&sW[kk * 260 + (tx << 2)];
      const float4 b1 = *(const float4*)&sW[kk * 260 + 128 + (tx << 2)];
      const float av[8] = {a0.x, a0.y, a0.z, a0.w, a1.x, a1.y, a1.z, a1.w};
      const float bv[8] = {b0.x, b0.y, b0.z, b0.w, b1.x, b1.y, b1.z, b1.w};
#pragma unroll
      for (int i = 0; i < 8; ++i)
#pragma unroll
        for (int c = 0; c < 8; ++c) acc[i][c] += av[i] * bv[c];
    }
  }

  const size_t bD = (size_t)(m0 >> 12) * (D_ * (size_t)S_);
  const int s0r = (int)(m0 & 4095) + (ty << 3);
#pragma unroll
  for (int c = 0; c < 8; ++c) {
    const int n = (c < 4) ? ((tx << 2) + c) : (128 + (tx << 2) + (c - 4));
    const float bn = bias[n];
    short8v h8, l8;
#pragma unroll
    for (int i = 0; i < 8; ++i) {
      const float y = acc[i][c] + bn;
      const unsigned short hh = f2bf(y);
      h8[i] = (short)hh; l8[i] = (short)f2bf(y - bf2f(hh));
    }
    *(short8v*)(vth + bD + (size_t)n * S_ + s0r) = h8;
    *(short8v*)(vtl + bD + (size_t)n * S_ + s0r) = l8;
  }
}

// ---------------------------------------------------------------------------
// MFMA flash attention, split-bf16 (3-term: Ah*Bh + Ah*Bl + Al*Bh).
// R3 STRUCTURE:
//   - 4 waves / 256 threads / 64 q-rows per block; grid (64,8) = 512 blocks
//     = 2 blocks/CU. Same 2 waves/SIMD as R2, but the waves belong to
//     INDEPENDENT blocks: barriers no longer phase-lock the whole SIMD,
//     so MFMA/VALU/LDS pipes overlap across blocks.
//   - K B-fragments read DIRECTLY from global (L2/L3-resident) with a
//     2-deep register prefetch ring (pf[kk&1], phase-stable as 8%2==0).
//     This deletes sK: -256 KB/iter of redundant LDS reads (8 waves read
//     identical frags), -33 KB LDS, -K staging phase.
//   - V staged in LDS (shared by 4 waves), register-prefetched across the
//     whole QK+softmax phase. sP is wave-private (no barrier needed).
//   - 2 raw barriers/iter protect only sV (WAR + publish). No vmcnt drain.
// ---------------------------------------------------------------------------
__global__ __launch_bounds__(256, 2) void flash_attn_mfma(
    const short* __restrict__ qh, const short* __restrict__ ql,
    const short* __restrict__ kh, const short* __restrict__ kl,
    const short* __restrict__ vth, const short* __restrict__ vtl,
    float* __restrict__ ctx) {
  __shared__ __align__(16) short sV[20480];    // Vth [256 d][40 pad] @0, Vtl @10240
  __shared__ unsigned int sP[4][16][36];       // 9 KB, per-wave P tiles

  const int t    = threadIdx.x;     // 0..255
  const int w    = t >> 6;          // 0..3
  const int lane = t & 63;
  const int m    = lane & 15;
  const int quad = lane >> 4;
  const int q0   = blockIdx.x * 64;
  const int b    = blockIdx.y;
  const size_t sd = (size_t)b * (S_ * (size_t)D_);
  const size_t bD = (size_t)b * (D_ * (size_t)S_);

  // Q A-frags, resident in registers for the whole kernel
  short8v aqh[8], aql[8];
  {
    const size_t row = sd + (size_t)(q0 + 16 * w + m) * D_;
#pragma unroll
    for (int kk = 0; kk < 8; ++kk) {
      const size_t off = row + kk * 32 + quad * 8;
      aqh[kk] = *(const short8v*)(qh + off);
      aql[kk] = *(const short8v*)(ql + off);
    }
  }

  float4v acc[16];
#pragma unroll
  for (int dt = 0; dt < 16; ++dt) acc[dt] = (float4v){0.f, 0.f, 0.f, 0.f};
  float m_i[4], l_i[4];
#pragma unroll
  for (int r = 0; r < 4; ++r) { m_i[r] = -INFINITY; l_i[r] = 0.f; }

  // ---- K direct-global B-frag bases (this lane's two j-rows) ----
  const short* kb0h = kh + sd + (size_t)m * D_ + quad * 8;
  const short* kb1h = kh + sd + (size_t)(16 + m) * D_ + quad * 8;
  const short* kb0l = kl + sd + (size_t)m * D_ + quad * 8;
  const short* kb1l = kl + sd + (size_t)(16 + m) * D_ + quad * 8;

  // 2-deep K prefetch ring (slot = kk&1; 8 kk-steps/iter keeps phase stable)
  short8v pbh0[2], pbh1[2], pbl0[2], pbl1[2];
#pragma unroll
  for (int i = 0; i < 2; ++i) {
    pbh0[i] = *(const short8v*)(kb0h + i * 32);
    pbh1[i] = *(const short8v*)(kb1h + i * 32);
    pbl0[i] = *(const short8v*)(kb0l + i * 32);
    pbl1[i] = *(const short8v*)(kb1l + i * 32);
  }

  // ---- V staging: thread t owns d-row t (64 B h + 64 B l per tile) ----
  const short* vgh = vth + bD + (size_t)t * S_;
  const short* vgl = vtl + bD + (size_t)t * S_;
  short8v rVh[4], rVl[4];
#pragma unroll
  for (int i = 0; i < 4; ++i) {
    rVh[i] = *(const short8v*)(vgh + (i << 3));
    rVl[i] = *(const short8v*)(vgl + (i << 3));
  }

  for (int jt = 0; jt < 128; ++jt) {
    const int koff  = jt << 13;                               // jt*32*256
    const int koffn = ((jt < 127) ? (jt + 1) : jt) << 13;

    // ---- scores: 16(q) x 32(j), D in 8 K-steps of 32; K from global ----
    float4v s0 = (float4v){0.f, 0.f, 0.f, 0.f};
    float4v s1 = (float4v){0.f, 0.f, 0.f, 0.f};
    __builtin_amdgcn_s_setprio(1);
#pragma unroll
    for (int kk = 0; kk < 8; ++kk) {
      const int sl = kk & 1;
      const short8v bh0 = pbh0[sl], bh1 = pbh1[sl];
      const short8v bl0 = pbl0[sl], bl1 = pbl1[sl];
      s0 = __builtin_amdgcn_mfma_f32_16x16x32_bf16(aqh[kk], bh0, s0, 0, 0, 0);
      s0 = __builtin_amdgcn_mfma_f32_16x16x32_bf16(aqh[kk], bl0, s0, 0, 0, 0);
      s0 = __builtin_amdgcn_mfma_f32_16x16x32_bf16(aql[kk], bh0, s0, 0, 0, 0);
      s1 = __builtin_amdgcn_mfma_f32_16x16x32_bf16(aqh[kk], bh1, s1, 0, 0, 0);
      s1 = __builtin_amdgcn_mfma_f32_16x16x32_bf16(aqh[kk], bl1, s1, 0, 0, 0);
      s1 = __builtin_amdgcn_mfma_f32_16x16x32_bf16(aql[kk], bh1, s1, 0, 0, 0);
      // refill slot with (jt, kk+2) or (jt+1, kk-6)
      const int nko = (kk < 6) ? (koff + (kk + 2) * 32) : (koffn + (kk - 6) * 32);
      pbh0[sl] = *(const short8v*)(kb0h + nko);
      pbh1[sl] = *(const short8v*)(kb1h + nko);
      pbl0[sl] = *(const short8v*)(kb0l + nko);
      pbl1[sl] = *(const short8v*)(kb1l + nko);
    }
    __builtin_amdgcn_s_setprio(0);

    // ---- online softmax (row r of this wave's tile = quad*4 + r) ----
    float alpha[4], pr0[4], pr1[4];
#pragma unroll
    for (int r = 0; r < 4; ++r) {
      float mx = fmaxf(s0[r], s1[r]);
      mx = fmaxf(mx, __shfl_xor(mx, 1, 64));
      mx = fmaxf(mx, __shfl_xor(mx, 2, 64));
      mx = fmaxf(mx, __shfl_xor(mx, 4, 64));
      mx = fmaxf(mx, __shfl_xor(mx, 8, 64));
      const float mnew = fmaxf(m_i[r], mx);
      alpha[r] = __expf(m_i[r] - mnew);
      m_i[r] = mnew;
      const float p0 = __expf(s0[r] - mnew);
      const float p1 = __expf(s1[r] - mnew);
      float rs = p0 + p1;
      rs += __shfl_xor(rs, 1, 64);
      rs += __shfl_xor(rs, 2, 64);
      rs += __shfl_xor(rs, 4, 64);
      rs += __shfl_xor(rs, 8, 64);
      l_i[r] = l_i[r] * alpha[r] + rs;
      pr0[r] = p0; pr1[r] = p1;
    }

    // ---- write split P to per-wave LDS (wave-private; no barrier) ----
#pragma unroll
    for (int r = 0; r < 4; ++r) {
      {
        const float p = pr0[r];
        const unsigned short hh = f2bf(p);
        const unsigned short ll = f2bf(p - bf2f(hh));
        sP[w][quad * 4 + r][m] = ((unsigned)hh << 16) | (unsigned)ll;
      }
      {
        const float p = pr1[r];
        const unsigned short hh = f2bf(p);
        const unsigned short ll = f2bf(p - bf2f(hh));
        sP[w][quad * 4 + r][16 + m] = ((unsigned)hh << 16) | (unsigned)ll;
      }
    }

    // ---- rescale ctx accumulators ----
#pragma unroll
    for (int dt = 0; dt < 16; ++dt)
#pragma unroll
      for (int r = 0; r < 4; ++r) acc[dt][r] *= alpha[r];

    // barA: all waves done with PV(jt-1) reads of sV. NO vmcnt drain.
    asm volatile("s_waitcnt lgkmcnt(0)" ::: "memory");
    __builtin_amdgcn_s_barrier();
    asm volatile("" ::: "memory");

    // ---- write prefetched V(jt) regs -> LDS (vmcnt waits land here;
    //      loads were issued a full iteration ago) ----
#pragma unroll
    for (int i = 0; i < 4; ++i) {
      *(short8v*)&sV[t * 40 + (i << 3)]         = rVh[i];
      *(short8v*)&sV[10240 + t * 40 + (i << 3)] = rVl[i];
    }
    // ---- issue V(jt+1) global loads (in flight across barB + PV + QK) ----
    {
      const int vo = ((jt < 127) ? (jt + 1) : jt) << 5;
#pragma unroll
      for (int i = 0; i < 4; ++i) {
        rVh[i] = *(const short8v*)(vgh + vo + (i << 3));
        rVl[i] = *(const short8v*)(vgl + vo + (i << 3));
      }
    }
    // barB: publish sV (and this wave's sP writes are drained).
    asm volatile("s_waitcnt lgkmcnt(0)" ::: "memory");
    __builtin_amdgcn_s_barrier();
    asm volatile("" ::: "memory");

    // ---- P A-frag: read back in A-layout, unpack hi/lo ----
    short8v ph, pl;
    {
      const uint4 pa = *(const uint4*)&sP[w][m][quad * 8];
      const uint4 pb = *(const uint4*)&sP[w][m][quad * 8 + 4];
      ph[0] = (short)(pa.x >> 16); pl[0] = (short)(pa.x & 0xffff);
      ph[1] = (short)(pa.y >> 16); pl[1] = (short)(pa.y & 0xffff);
      ph[2] = (short)(pa.z >> 16); pl[2] = (short)(pa.z & 0xffff);
      ph[3] = (short)(pa.w >> 16); pl[3] = (short)(pa.w & 0xffff);
      ph[4] = (short)(pb.x >> 16); pl[4] = (short)(pb.x & 0xffff);
      ph[5] = (short)(pb.y >> 16); pl[5] = (short)(pb.y & 0xffff);
      ph[6] = (short)(pb.z >> 16); pl[6] = (short)(pb.z & 0xffff);
      ph[7] = (short)(pb.w >> 16); pl[7] = (short)(pb.w & 0xffff);
    }

    // ---- PV: ctx[16 q][256 d] += P[16 q][32 j] @ V[32 j][256 d] ----
    __builtin_amdgcn_s_setprio(1);
#pragma unroll
    for (int dt = 0; dt < 16; ++dt) {
      const int vr = (dt * 16 + m) * 40 + quad * 8;
      const short8v bh = *(const short8v*)&sV[vr];
      const short8v bl = *(const short8v*)&sV[10240 + vr];
      acc[dt] = __builtin_amdgcn_mfma_f32_16x16x32_bf16(ph, bh, acc[dt], 0, 0, 0);
      acc[dt] = __builtin_amdgcn_mfma_f32_16x16x32_bf16(ph, bl, acc[dt], 0, 0, 0);
      acc[dt] = __builtin_amdgcn_mfma_f32_16x16x32_bf16(pl, bh, acc[dt], 0, 0, 0);
    }
    __builtin_amdgcn_s_setprio(0);
  }

  // ---- finalize: divide by l, store ctx (C-layout scatter, 64B granules) ----
#pragma unroll
  for (int r = 0; r < 4; ++r) {
    const float inv = 1.0f / l_i[r];
    float* cp = ctx + sd + (size_t)(q0 + 16 * w + quad * 4 + r) * D_ + m;
#pragma unroll
    for (int dt = 0; dt < 16; ++dt) cp[dt * 16] = acc[dt][r] * inv;
  }
}

// ---------------------------------------------------------------------------
// w[row] = dot(logits[row,:], cv)
// ---------------------------------------------------------------------------
__global__ __launch_bounds__(256) void wdot_kernel(
    const float* __restrict__ logits, const float* __restrict__ cv,
    float* __restrict__ w) {
  const int t    = threadIdx.x;
  const int wave = t >> 6, lane = t & 63;
  const size_t row = (size_t)blockIdx.x * 4 + wave;
  const float4 l4 = *(const float4*)(logits + row * 256 + (lane << 2));
  const float4 c4 = *(const float4*)(cv + (lane << 2));
  float p = l4.x * c4.x + l4.y * c4.y + l4.z * c4.z + l4.w * c4.w;
#pragma unroll
  for (int off = 32; off > 0; off >>= 1) p += __shfl_down(p, off, 64);
  if (lane == 0) w[row] = p;
}

// ---------------------------------------------------------------------------
// softmax over sequence dim per batch (in place on w)
// ---------------------------------------------------------------------------
__global__ __launch_bounds__(256) void seq_softmax_kernel(float* __restrict__ w) {
  __shared__ float red[4];
  const int b = blockIdx.x, t = threadIdx.x;
  const int wave = t >> 6, lane = t & 63;
  float* wb = w + (size_t)b * S_;
  float vals[16];
  float mx = -INFINITY;
#pragma unroll
  for (int i = 0; i < 16; ++i) {
    vals[i] = wb[t + (i << 8)];
    mx = fmaxf(mx, vals[i]);
  }
#pragma unroll
  for (int off = 32; off > 0; off >>= 1) mx = fmaxf(mx, __shfl_xor(mx, off, 64));
  if (lane == 0) red[wave] = mx;
  __syncthreads();
  const float M = fmaxf(fmaxf(red[0], red[1]), fmaxf(red[2], red[3]));
  float sum = 0.f;
#pragma unroll
  for (int i = 0; i < 16; ++i) {
    vals[i] = __expf(vals[i] - M);
    sum += vals[i];
  }
#pragma unroll
  for (int off = 32; off > 0; off >>= 1) sum += __shfl_xor(sum, off, 64);
  __syncthreads();
  if (lane == 0) red[wave] = sum;
  __syncthreads();
  const float inv = 1.0f / (red[0] + red[1] + red[2] + red[3]);
#pragma unroll
  for (int i = 0; i < 16; ++i) wb[t + (i << 8)] = vals[i] * inv;
}

// ---------------------------------------------------------------------------
// out[b,s,:] *= nw[b,s]
// ---------------------------------------------------------------------------
__global__ __launch_bounds__(256) void scale_kernel(
    float* __restrict__ out, const float* __restrict__ nw) {
  const size_t g = (size_t)blockIdx.x * 256 + threadIdx.x;
  float4* o4 = (float4*)out;
  float4 vv = o4[g];
  const float sc = nw[g >> 6];
  vv.x *= sc; vv.y *= sc; vv.z *= sc; vv.w *= sc;
  o4[g] = vv;
}

// ---------------------------------------------------------------------------
extern "C" void kernel_launch(void* const* d_in, const int* in_sizes, int n_in,
                              void* d_out, int out_size, void* d_ws, size_t ws_size,
                              hipStream_t stream) {
  const float* x  = (const float*)d_in[0];
  const float* Wq = (const float*)d_in[1];
  const float* bq = (const float*)d_in[2];
  const float* Wk = (const float*)d_in[3];
  const float* bk = (const float*)d_in[4];
  const float* Wv = (const float*)d_in[5];
  const float* bv = (const float*)d_in[6];
  const float* Wo = (const float*)d_in[7];
  const float* bo = (const float*)d_in[8];
  const float* cv = (const float*)d_in[9];
  float* out = (float*)d_out;

  const size_t N = (size_t)B_ * S_ * D_;  // 8,388,608 elements
  short* qh  = (short*)d_ws;      // [b][s][d] bf16 hi (Q pre-scaled by 1/16)
  short* ql  = qh + N;            // [b][s][d] bf16 lo
  short* kh  = ql + N;            // [b][s][d]
  short* kl  = kh + N;
  short* vth = kl + N;            // [b][d][s]
  short* vtl = vth + N;
  float* ctx = (float*)(vtl + N); // [b][s][d] fp32
  float* w   = ctx + N;           // B*S floats

  proj_split_nat_kernel<<<512, 256, 0, stream>>>(x, Wq, bq, qh, ql, 0.0625f);
  proj_split_nat_kernel<<<512, 256, 0, stream>>>(x, Wk, bk, kh, kl, 1.0f);
  proj_split_t_kernel<<<512, 256, 0, stream>>>(x, Wv, bv, vth, vtl);
  flash_attn_mfma<<<dim3(64, 8), 256, 0, stream>>>(qh, ql, kh, kl, vth, vtl, ctx);
  gemm_bias_kernel<<<512, 256, 0, stream>>>(ctx, Wo, bo, out);
  wdot_kernel<<<8192, 256, 0, stream>>>(out, cv, w);
  seq_softmax_kernel<<<8, 256, 0, stream>>>(w);
  scale_kernel<<<8192, 256, 0, stream>>>(out, w);
}

// Round 4
// 692.944 us; speedup vs baseline: 2.0666x; 2.0666x over previous
//
#include <hip/hip_runtime.h>
#include <math.h>
#include <cstddef>
#include <cstdint>

#define B_ 8
#define S_ 4096
#define D_ 256

typedef __attribute__((ext_vector_type(8))) short short8v;   // 8 bf16 (4 VGPR)
typedef __attribute__((ext_vector_type(4))) short short4v;   // 4 bf16 (8 B)
typedef __attribute__((ext_vector_type(4))) float float4v;   // MFMA C/D

// float -> bf16 (RNE) and back, on bit patterns
__device__ __forceinline__ unsigned short f2bf(float f) {
  unsigned u = __float_as_uint(f);
  return (unsigned short)((u + 0x7FFF + ((u >> 16) & 1)) >> 16);
}
__device__ __forceinline__ float bf2f(unsigned short h) {
  return __uint_as_float((unsigned)h << 16);
}
__device__ __forceinline__ unsigned packp(float p) {
  const unsigned short hh = f2bf(p);
  const unsigned short ll = f2bf(p - bf2f(hh));
  return ((unsigned)hh << 16) | (unsigned)ll;
}

// ---------------------------------------------------------------------------
// fp32 GEMM (used for Wo): C[M,256] = A @ W + bias, natural layout.
// ---------------------------------------------------------------------------
__global__ __launch_bounds__(256, 2) void gemm_bias_kernel(
    const float* __restrict__ A, const float* __restrict__ W,
    const float* __restrict__ bias, float* __restrict__ C) {
  __shared__ __align__(16) float sA[32 * 68];
  __shared__ __align__(16) float sW[32 * 260];
  const int t  = threadIdx.x;
  const int tx = t & 31;
  const int ty = t >> 5;
  const size_t m0 = (size_t)blockIdx.x * 64;

  float acc[8][8] = {};

  for (int kc = 0; kc < 8; ++kc) {
    const int k0 = kc << 5;
    __syncthreads();
#pragma unroll
    for (int l = 0; l < 2; ++l) {
      const int idx = t + (l << 8);
      const int r = idx >> 3, cf = (idx & 7) << 2;
      const float4 a4 = *(const float4*)(A + (m0 + r) * 256 + k0 + cf);
      sA[(cf + 0) * 68 + r] = a4.x;
      sA[(cf + 1) * 68 + r] = a4.y;
      sA[(cf + 2) * 68 + r] = a4.z;
      sA[(cf + 3) * 68 + r] = a4.w;
    }
#pragma unroll
    for (int l = 0; l < 8; ++l) {
      const int idx = t + (l << 8);
      const int kr = idx >> 6, nc = (idx & 63) << 2;
      *(float4*)&sW[kr * 260 + nc] =
          *(const float4*)(W + (size_t)(k0 + kr) * 256 + nc);
    }
    __syncthreads();
#pragma unroll
    for (int kk = 0; kk < 32; ++kk) {
      const float4 a0 = *(const float4*)&sA[kk * 68 + (ty << 3)];
      const float4 a1 = *(const float4*)&sA[kk * 68 + (ty << 3) + 4];
      const float4 b0 = *(const float4*)&sW[kk * 260 + (tx << 2)];
      const float4 b1 = *(const float4*)&sW[kk * 260 + 128 + (tx << 2)];
      const float av[8] = {a0.x, a0.y, a0.z, a0.w, a1.x, a1.y, a1.z, a1.w};
      const float bv[8] = {b0.x, b0.y, b0.z, b0.w, b1.x, b1.y, b1.z, b1.w};
#pragma unroll
      for (int i = 0; i < 8; ++i)
#pragma unroll
        for (int c = 0; c < 8; ++c) acc[i][c] += av[i] * bv[c];
    }
  }

  const float4 bb0 = *(const float4*)(bias + (tx << 2));
  const float4 bb1 = *(const float4*)(bias + 128 + (tx << 2));
#pragma unroll
  for (int i = 0; i < 8; ++i) {
    float4 o0, o1;
    o0.x = acc[i][0] + bb0.x; o0.y = acc[i][1] + bb0.y;
    o0.z = acc[i][2] + bb0.z; o0.w = acc[i][3] + bb0.w;
    o1.x = acc[i][4] + bb1.x; o1.y = acc[i][5] + bb1.y;
    o1.z = acc[i][6] + bb1.z; o1.w = acc[i][7] + bb1.w;
    float* cp = C + (m0 + (ty << 3) + i) * 256;
    *(float4*)(cp + (tx << 2)) = o0;
    *(float4*)(cp + 128 + (tx << 2)) = o1;
  }
}

// ---------------------------------------------------------------------------
// Projection GEMM -> split-bf16 NATURAL output [b][s][d]: yh + yl (hi/lo).
// scale folded in before the split (Q uses 1/16, K uses 1).
// ---------------------------------------------------------------------------
__global__ __launch_bounds__(256, 2) void proj_split_nat_kernel(
    const float* __restrict__ A, const float* __restrict__ W,
    const float* __restrict__ bias, short* __restrict__ outh,
    short* __restrict__ outl, float scale) {
  __shared__ __align__(16) float sA[32 * 68];
  __shared__ __align__(16) float sW[32 * 260];
  const int t  = threadIdx.x;
  const int tx = t & 31;
  const int ty = t >> 5;
  const size_t m0 = (size_t)blockIdx.x * 64;

  float acc[8][8] = {};

  for (int kc = 0; kc < 8; ++kc) {
    const int k0 = kc << 5;
    __syncthreads();
#pragma unroll
    for (int l = 0; l < 2; ++l) {
      const int idx = t + (l << 8);
      const int r = idx >> 3, cf = (idx & 7) << 2;
      const float4 a4 = *(const float4*)(A + (m0 + r) * 256 + k0 + cf);
      sA[(cf + 0) * 68 + r] = a4.x;
      sA[(cf + 1) * 68 + r] = a4.y;
      sA[(cf + 2) * 68 + r] = a4.z;
      sA[(cf + 3) * 68 + r] = a4.w;
    }
#pragma unroll
    for (int l = 0; l < 8; ++l) {
      const int idx = t + (l << 8);
      const int kr = idx >> 6, nc = (idx & 63) << 2;
      *(float4*)&sW[kr * 260 + nc] =
          *(const float4*)(W + (size_t)(k0 + kr) * 256 + nc);
    }
    __syncthreads();
#pragma unroll
    for (int kk = 0; kk < 32; ++kk) {
      const float4 a0 = *(const float4*)&sA[kk * 68 + (ty << 3)];
      const float4 a1 = *(const float4*)&sA[kk * 68 + (ty << 3) + 4];
      const float4 b0 = *(const float4*)&sW[kk * 260 + (tx << 2)];
      const float4 b1 = *(const float4*)&sW[kk * 260 + 128 + (tx << 2)];
      const float av[8] = {a0.x, a0.y, a0.z, a0.w, a1.x, a1.y, a1.z, a1.w};
      const float bv[8] = {b0.x, b0.y, b0.z, b0.w, b1.x, b1.y, b1.z, b1.w};
#pragma unroll
      for (int i = 0; i < 8; ++i)
#pragma unroll
        for (int c = 0; c < 8; ++c) acc[i][c] += av[i] * bv[c];
    }
  }

  const float4 bb0 = *(const float4*)(bias + (tx << 2));
  const float4 bb1 = *(const float4*)(bias + 128 + (tx << 2));
  const float bb0v[4] = {bb0.x, bb0.y, bb0.z, bb0.w};
  const float bb1v[4] = {bb1.x, bb1.y, bb1.z, bb1.w};
#pragma unroll
  for (int i = 0; i < 8; ++i) {
    const size_t ro = (m0 + (ty << 3) + i) * 256;
    short4v h0, l0, h1, l1;
#pragma unroll
    for (int c = 0; c < 4; ++c) {
      const float y0 = (acc[i][c] + bb0v[c]) * scale;
      const unsigned short hh0 = f2bf(y0);
      h0[c] = (short)hh0; l0[c] = (short)f2bf(y0 - bf2f(hh0));
      const float y1 = (acc[i][4 + c] + bb1v[c]) * scale;
      const unsigned short hh1 = f2bf(y1);
      h1[c] = (short)hh1; l1[c] = (short)f2bf(y1 - bf2f(hh1));
    }
    *(short4v*)(outh + ro + (tx << 2)) = h0;
    *(short4v*)(outl + ro + (tx << 2)) = l0;
    *(short4v*)(outh + ro + 128 + (tx << 2)) = h1;
    *(short4v*)(outl + ro + 128 + (tx << 2)) = l1;
  }
}

// ---------------------------------------------------------------------------
// V projection -> split-bf16 TRANSPOSED output [b][d][s]: vth + vtl.
// ---------------------------------------------------------------------------
__global__ __launch_bounds__(256, 2) void proj_split_t_kernel(
    const float* __restrict__ A, const float* __restrict__ W,
    const float* __restrict__ bias, short* __restrict__ vth,
    short* __restrict__ vtl) {
  __shared__ __align__(16) float sA[32 * 68];
  __shared__ __align__(16) float sW[32 * 260];
  const int t  = threadIdx.x;
  const int tx = t & 31;
  const int ty = t >> 5;
  const size_t m0 = (size_t)blockIdx.x * 64;

  float acc[8][8] = {};

  for (int kc = 0; kc < 8; ++kc) {
    const int k0 = kc << 5;
    __syncthreads();
#pragma unroll
    for (int l = 0; l < 2; ++l) {
      const int idx = t + (l << 8);
      const int r = idx >> 3, cf = (idx & 7) << 2;
      const float4 a4 = *(const float4*)(A + (m0 + r) * 256 + k0 + cf);
      sA[(cf + 0) * 68 + r] = a4.x;
      sA[(cf + 1) * 68 + r] = a4.y;
      sA[(cf + 2) * 68 + r] = a4.z;
      sA[(cf + 3) * 68 + r] = a4.w;
    }
#pragma unroll
    for (int l = 0; l < 8; ++l) {
      const int idx = t + (l << 8);
      const int kr = idx >> 6, nc = (idx & 63) << 2;
      *(float4*)&sW[kr * 260 + nc] =
          *(const float4*)(W + (size_t)(k0 + kr) * 256 + nc);
    }
    __syncthreads();
#pragma unroll
    for (int kk = 0; kk < 32; ++kk) {
      const float4 a0 = *(const float4*)&sA[kk * 68 + (ty << 3)];
      const float4 a1 = *(const float4*)&sA[kk * 68 + (ty << 3) + 4];
      const float4 b0 = *(const float4*)&sW[kk * 260 + (tx << 2)];
      const float4 b1 = *(const float4*)&sW[kk * 260 + 128 + (tx << 2)];
      const float av[8] = {a0.x, a0.y, a0.z, a0.w, a1.x, a1.y, a1.z, a1.w};
      const float bv[8] = {b0.x, b0.y, b0.z, b0.w, b1.x, b1.y, b1.z, b1.w};
#pragma unroll
      for (int i = 0; i < 8; ++i)
#pragma unroll
        for (int c = 0; c < 8; ++c) acc[i][c] += av[i] * bv[c];
    }
  }

  const size_t bD = (size_t)(m0 >> 12) * (D_ * (size_t)S_);
  const int s0r = (int)(m0 & 4095) + (ty << 3);
#pragma unroll
  for (int c = 0; c < 8; ++c) {
    const int n = (c < 4) ? ((tx << 2) + c) : (128 + (tx << 2) + (c - 4));
    const float bn = bias[n];
    short8v h8, l8;
#pragma unroll
    for (int i = 0; i < 8; ++i) {
      const float y = acc[i][c] + bn;
      const unsigned short hh = f2bf(y);
      h8[i] = (short)hh; l8[i] = (short)f2bf(y - bf2f(hh));
    }
    *(short8v*)(vth + bD + (size_t)n * S_ + s0r) = h8;
    *(short8v*)(vtl + bD + (size_t)n * S_ + s0r) = l8;
  }
}

// ---------------------------------------------------------------------------
// MFMA flash attention, split-bf16 (3-term: Ah*Bh + Ah*Bl + Al*Bh).
// R4 = R2 skeleton (8 waves/512thr, LDS-staged K+V, reg prefetch, raw
// barriers) + swapped-operand QK + slim softmax path:
//   - QK computed as mfma(K_frag, Q_frag) -> S^T: SAME LDS reads & Q regs
//     (A/B frag layouts are byte-identical), but each lane now holds 8
//     scores of ITS OWN q-row (row = lane&15).
//   - softmax row-reduce: 7 in-lane fmax + 2 shfl_xor (was 32 shfls/iter).
//   - P round-trip: 2x ds_write_b128 per lane (was 8x b32); read unchanged.
//   - l_i via ones-column PV (2 extra MFMA, B = bf16 1.0): row-sums of P
//     accumulate in PV C-layout == exactly what finalize needs. No sum
//     shuffles, no l bookkeeping, auto-rescaled with acc.
//   - defer-max (THR=8): wave-uniform skip of rescale; alpha redistributed
//     C-layout-wise via 4 shfl only on the rare rescale iterations.
// ---------------------------------------------------------------------------
__global__ __launch_bounds__(512, 2) void flash_attn_mfma(
    const short* __restrict__ qh, const short* __restrict__ ql,
    const short* __restrict__ kh, const short* __restrict__ kl,
    const short* __restrict__ vth, const short* __restrict__ vtl,
    float* __restrict__ ctx) {
  __shared__ __align__(16) short sK[16896];    // Kh [32 j][264 pad] @0, Kl @8448
  __shared__ __align__(16) short sV[20480];    // Vth [256 d][40 pad] @0, Vtl @10240
  __shared__ unsigned int sP[8][16][36];       // 18 KB, per-wave P tiles (row=q-row)

  const int t    = threadIdx.x;
  const int w    = t >> 6;          // 0..7
  const int lane = t & 63;
  const int m    = lane & 15;
  const int quad = lane >> 4;
  const int q0   = blockIdx.x * 128;
  const int b    = blockIdx.y;
  const size_t sd = (size_t)b * (S_ * (size_t)D_);
  const size_t bD = (size_t)b * (D_ * (size_t)S_);

  // Q frags (per-wave register resident; used as the MFMA *B* operand now —
  // same bytes as the old A-frag layout)
  short8v aqh[8], aql[8];
  {
    const size_t row = sd + (size_t)(q0 + 16 * w + m) * D_;
#pragma unroll
    for (int kk = 0; kk < 8; ++kk) {
      const size_t off = row + kk * 32 + quad * 8;
      aqh[kk] = *(const short8v*)(qh + off);
      aql[kk] = *(const short8v*)(ql + off);
    }
  }

  // ones B-frag for the l-column (bf16 1.0 in every element)
  short8v ones;
#pragma unroll
  for (int e = 0; e < 8; ++e) ones[e] = (short)0x3F80;

  float4v acc[16];
#pragma unroll
  for (int dt = 0; dt < 16; ++dt) acc[dt] = (float4v){0.f, 0.f, 0.f, 0.f};
  float4v accl = (float4v){0.f, 0.f, 0.f, 0.f};   // l for rows quad*4+r
  float m_i = -INFINITY;                          // running max of row (lane&15)

  // ---- staging addresses (512 threads) ----
  const int kr0 = t >> 5;            // 0..15
  const int kc0 = (t & 31) << 3;     // 0..248
  const int vd  = t >> 1;            // 0..255
  const int vjh = (t & 1) << 4;      // 0 or 16

  // prefetch registers
  short8v rKh0, rKh1, rKl0, rKl1;
  short8v rVh0, rVh1, rVl0, rVl1;

  // prologue: issue K(0) loads
  {
    const size_t g0 = sd + (size_t)kr0 * D_ + kc0;
    const size_t g1 = sd + (size_t)(16 + kr0) * D_ + kc0;
    rKh0 = *(const short8v*)(kh + g0);
    rKh1 = *(const short8v*)(kh + g1);
    rKl0 = *(const short8v*)(kl + g0);
    rKl1 = *(const short8v*)(kl + g1);
  }

  for (int jt = 0; jt < 128; ++jt) {
    const int j0 = jt << 5;

    // ---- write prefetched K(jt) regs -> LDS (vmcnt wait auto-inserted) ----
    *(short8v*)&sK[kr0 * 264 + kc0]               = rKh0;
    *(short8v*)&sK[(16 + kr0) * 264 + kc0]        = rKh1;
    *(short8v*)&sK[8448 + kr0 * 264 + kc0]        = rKl0;
    *(short8v*)&sK[8448 + (16 + kr0) * 264 + kc0] = rKl1;
    // ---- issue V(jt) global loads (stay in flight across bar1 + QK) ----
    {
      const size_t g = bD + (size_t)vd * S_ + j0 + vjh;
      rVh0 = *(const short8v*)(vth + g);
      rVh1 = *(const short8v*)(vth + g + 8);
      rVl0 = *(const short8v*)(vtl + g);
      rVl1 = *(const short8v*)(vtl + g + 8);
    }
    // bar1: publish K(jt); PV(jt-1) readers are done. NO vmcnt drain.
    asm volatile("s_waitcnt lgkmcnt(0)" ::: "memory");
    __builtin_amdgcn_s_barrier();
    asm volatile("" ::: "memory");

    // ---- scores SWAPPED: S^T = K·Q^T. Lane holds S[row=m][j=4q+r] in s0[r]
    //      and S[m][16+4q+r] in s1[r]. Same LDS reads as before. ----
    float4v s0 = (float4v){0.f, 0.f, 0.f, 0.f};
    float4v s1 = (float4v){0.f, 0.f, 0.f, 0.f};
    __builtin_amdgcn_s_setprio(1);
#pragma unroll
    for (int kk = 0; kk < 8; ++kk) {
      const int co = kk * 32 + quad * 8;
      const short8v bh0 = *(const short8v*)&sK[m * 264 + co];
      const short8v bl0 = *(const short8v*)&sK[8448 + m * 264 + co];
      const short8v bh1 = *(const short8v*)&sK[(16 + m) * 264 + co];
      const short8v bl1 = *(const short8v*)&sK[8448 + (16 + m) * 264 + co];
      s0 = __builtin_amdgcn_mfma_f32_16x16x32_bf16(bh0, aqh[kk], s0, 0, 0, 0);
      s0 = __builtin_amdgcn_mfma_f32_16x16x32_bf16(bh0, aql[kk], s0, 0, 0, 0);
      s0 = __builtin_amdgcn_mfma_f32_16x16x32_bf16(bl0, aqh[kk], s0, 0, 0, 0);
      s1 = __builtin_amdgcn_mfma_f32_16x16x32_bf16(bh1, aqh[kk], s1, 0, 0, 0);
      s1 = __builtin_amdgcn_mfma_f32_16x16x32_bf16(bh1, aql[kk], s1, 0, 0, 0);
      s1 = __builtin_amdgcn_mfma_f32_16x16x32_bf16(bl1, aqh[kk], s1, 0, 0, 0);
    }
    __builtin_amdgcn_s_setprio(0);

    // ---- online softmax, per-lane row m ----
    {
      float mx = fmaxf(fmaxf(fmaxf(s0[0], s0[1]), fmaxf(s0[2], s0[3])),
                       fmaxf(fmaxf(s1[0], s1[1]), fmaxf(s1[2], s1[3])));
      mx = fmaxf(mx, __shfl_xor(mx, 16, 64));
      mx = fmaxf(mx, __shfl_xor(mx, 32, 64));
      // defer-max: rescale only when some row grew past m_i + 8
      if (__any(mx > m_i + 8.0f)) {
        const float mnew = fmaxf(m_i, mx);
        const float alpha = __expf(m_i - mnew);
        m_i = mnew;
        // acc rows are quad*4+r; alpha lives at lane (row, ·). Pull alphas
        // for rows 4q+r from lane quad*16 + (4*quad + r) = 20*quad + r.
        float al[4];
#pragma unroll
        for (int r = 0; r < 4; ++r) al[r] = __shfl(alpha, 20 * quad + r, 64);
#pragma unroll
        for (int dt = 0; dt < 16; ++dt)
#pragma unroll
          for (int r = 0; r < 4; ++r) acc[dt][r] *= al[r];
#pragma unroll
        for (int r = 0; r < 4; ++r) accl[r] *= al[r];
      }
    }

    // ---- P = exp(s - m_i), pack hi|lo, 2x b128 to per-wave LDS ----
    {
      uint4 w0, w1;
      w0.x = packp(__expf(s0[0] - m_i));
      w0.y = packp(__expf(s0[1] - m_i));
      w0.z = packp(__expf(s0[2] - m_i));
      w0.w = packp(__expf(s0[3] - m_i));
      w1.x = packp(__expf(s1[0] - m_i));
      w1.y = packp(__expf(s1[1] - m_i));
      w1.z = packp(__expf(s1[2] - m_i));
      w1.w = packp(__expf(s1[3] - m_i));
      *(uint4*)&sP[w][m][4 * quad]      = w0;   // j = 4q..4q+3
      *(uint4*)&sP[w][m][16 + 4 * quad] = w1;   // j = 16+4q..+3
    }

    // ---- write prefetched V(jt) regs -> LDS (vmcnt waits land here,
    //      ~2000 cycles after issue -> latency hidden under QK+softmax) ----
    *(short8v*)&sV[vd * 40 + vjh]               = rVh0;
    *(short8v*)&sV[vd * 40 + vjh + 8]           = rVh1;
    *(short8v*)&sV[10240 + vd * 40 + vjh]       = rVl0;
    *(short8v*)&sV[10240 + vd * 40 + vjh + 8]   = rVl1;
    // ---- issue K(jt+1) global loads (in flight across bar2 + PV) ----
    if (jt < 127) {
      const int j0n = j0 + 32;
      const size_t g0 = sd + (size_t)(j0n + kr0) * D_ + kc0;
      const size_t g1 = sd + (size_t)(j0n + 16 + kr0) * D_ + kc0;
      rKh0 = *(const short8v*)(kh + g0);
      rKh1 = *(const short8v*)(kh + g1);
      rKl0 = *(const short8v*)(kl + g0);
      rKl1 = *(const short8v*)(kl + g1);
    }
    // bar2: publish V(jt) + sP writes drained (lgkmcnt(0) covers ds_writes).
    asm volatile("s_waitcnt lgkmcnt(0)" ::: "memory");
    __builtin_amdgcn_s_barrier();
    asm volatile("" ::: "memory");

    // ---- P A-frag: lane (m,q) reads P[row m][j=8q..8q+7] (unchanged) ----
    short8v ph, pl;
    {
      const uint4 pa = *(const uint4*)&sP[w][m][quad * 8];
      const uint4 pb = *(const uint4*)&sP[w][m][quad * 8 + 4];
      ph[0] = (short)(pa.x >> 16); pl[0] = (short)(pa.x & 0xffff);
      ph[1] = (short)(pa.y >> 16); pl[1] = (short)(pa.y & 0xffff);
      ph[2] = (short)(pa.z >> 16); pl[2] = (short)(pa.z & 0xffff);
      ph[3] = (short)(pa.w >> 16); pl[3] = (short)(pa.w & 0xffff);
      ph[4] = (short)(pb.x >> 16); pl[4] = (short)(pb.x & 0xffff);
      ph[5] = (short)(pb.y >> 16); pl[5] = (short)(pb.y & 0xffff);
      ph[6] = (short)(pb.z >> 16); pl[6] = (short)(pb.z & 0xffff);
      ph[7] = (short)(pb.w >> 16); pl[7] = (short)(pb.w & 0xffff);
    }

    // ---- PV: ctx[16 q][256 d] += P @ V; + ones-column for l ----
    __builtin_amdgcn_s_setprio(1);
    accl = __builtin_amdgcn_mfma_f32_16x16x32_bf16(ph, ones, accl, 0, 0, 0);
    accl = __builtin_amdgcn_mfma_f32_16x16x32_bf16(pl, ones, accl, 0, 0, 0);
#pragma unroll
    for (int dt = 0; dt < 16; ++dt) {
      const int vr = (dt * 16 + m) * 40 + quad * 8;
      const short8v bh = *(const short8v*)&sV[vr];
      const short8v bl = *(const short8v*)&sV[10240 + vr];
      acc[dt] = __builtin_amdgcn_mfma_f32_16x16x32_bf16(ph, bh, acc[dt], 0, 0, 0);
      acc[dt] = __builtin_amdgcn_mfma_f32_16x16x32_bf16(ph, bl, acc[dt], 0, 0, 0);
      acc[dt] = __builtin_amdgcn_mfma_f32_16x16x32_bf16(pl, bh, acc[dt], 0, 0, 0);
    }
    __builtin_amdgcn_s_setprio(0);
  }

  // ---- finalize: divide by l (accl[r] = l of row quad*4+r), store ctx ----
#pragma unroll
  for (int r = 0; r < 4; ++r) {
    const float inv = 1.0f / accl[r];
    float* cp = ctx + sd + (size_t)(q0 + 16 * w + quad * 4 + r) * D_ + m;
#pragma unroll
    for (int dt = 0; dt < 16; ++dt) cp[dt * 16] = acc[dt][r] * inv;
  }
}

// ---------------------------------------------------------------------------
// w[row] = dot(logits[row,:], cv)
// ---------------------------------------------------------------------------
__global__ __launch_bounds__(256) void wdot_kernel(
    const float* __restrict__ logits, const float* __restrict__ cv,
    float* __restrict__ w) {
  const int t    = threadIdx.x;
  const int wave = t >> 6, lane = t & 63;
  const size_t row = (size_t)blockIdx.x * 4 + wave;
  const float4 l4 = *(const float4*)(logits + row * 256 + (lane << 2));
  const float4 c4 = *(const float4*)(cv + (lane << 2));
  float p = l4.x * c4.x + l4.y * c4.y + l4.z * c4.z + l4.w * c4.w;
#pragma unroll
  for (int off = 32; off > 0; off >>= 1) p += __shfl_down(p, off, 64);
  if (lane == 0) w[row] = p;
}

// ---------------------------------------------------------------------------
// softmax over sequence dim per batch (in place on w)
// ---------------------------------------------------------------------------
__global__ __launch_bounds__(256) void seq_softmax_kernel(float* __restrict__ w) {
  __shared__ float red[4];
  const int b = blockIdx.x, t = threadIdx.x;
  const int wave = t >> 6, lane = t & 63;
  float* wb = w + (size_t)b * S_;
  float vals[16];
  float mx = -INFINITY;
#pragma unroll
  for (int i = 0; i < 16; ++i) {
    vals[i] = wb[t + (i << 8)];
    mx = fmaxf(mx, vals[i]);
  }
#pragma unroll
  for (int off = 32; off > 0; off >>= 1) mx = fmaxf(mx, __shfl_xor(mx, off, 64));
  if (lane == 0) red[wave] = mx;
  __syncthreads();
  const float M = fmaxf(fmaxf(red[0], red[1]), fmaxf(red[2], red[3]));
  float sum = 0.f;
#pragma unroll
  for (int i = 0; i < 16; ++i) {
    vals[i] = __expf(vals[i] - M);
    sum += vals[i];
  }
#pragma unroll
  for (int off = 32; off > 0; off >>= 1) sum += __shfl_xor(sum, off, 64);
  __syncthreads();
  if (lane == 0) red[wave] = sum;
  __syncthreads();
  const float inv = 1.0f / (red[0] + red[1] + red[2] + red[3]);
#pragma unroll
  for (int i = 0; i < 16; ++i) wb[t + (i << 8)] = vals[i] * inv;
}

// ---------------------------------------------------------------------------
// out[b,s,:] *= nw[b,s]
// ---------------------------------------------------------------------------
__global__ __launch_bounds__(256) void scale_kernel(
    float* __restrict__ out, const float* __restrict__ nw) {
  const size_t g = (size_t)blockIdx.x * 256 + threadIdx.x;
  float4* o4 = (float4*)out;
  float4 vv = o4[g];
  const float sc = nw[g >> 6];
  vv.x *= sc; vv.y *= sc; vv.z *= sc; vv.w *= sc;
  o4[g] = vv;
}

// ---------------------------------------------------------------------------
extern "C" void kernel_launch(void* const* d_in, const int* in_sizes, int n_in,
                              void* d_out, int out_size, void* d_ws, size_t ws_size,
                              hipStream_t stream) {
  const float* x  = (const float*)d_in[0];
  const float* Wq = (const float*)d_in[1];
  const float* bq = (const float*)d_in[2];
  const float* Wk = (const float*)d_in[3];
  const float* bk = (const float*)d_in[4];
  const float* Wv = (const float*)d_in[5];
  const float* bv = (const float*)d_in[6];
  const float* Wo = (const float*)d_in[7];
  const float* bo = (const float*)d_in[8];
  const float* cv = (const float*)d_in[9];
  float* out = (float*)d_out;

  const size_t N = (size_t)B_ * S_ * D_;  // 8,388,608 elements
  short* qh  = (short*)d_ws;      // [b][s][d] bf16 hi (Q pre-scaled by 1/16)
  short* ql  = qh + N;            // [b][s][d] bf16 lo
  short* kh  = ql + N;            // [b][s][d]
  short* kl  = kh + N;
  short* vth = kl + N;            // [b][d][s]
  short* vtl = vth + N;
  float* ctx = (float*)(vtl + N); // [b][s][d] fp32
  float* w   = ctx + N;           // B*S floats

  proj_split_nat_kernel<<<512, 256, 0, stream>>>(x, Wq, bq, qh, ql, 0.0625f);
  proj_split_nat_kernel<<<512, 256, 0, stream>>>(x, Wk, bk, kh, kl, 1.0f);
  proj_split_t_kernel<<<512, 256, 0, stream>>>(x, Wv, bv, vth, vtl);
  flash_attn_mfma<<<dim3(32, 8), 512, 0, stream>>>(qh, ql, kh, kl, vth, vtl, ctx);
  gemm_bias_kernel<<<512, 256, 0, stream>>>(ctx, Wo, bo, out);
  wdot_kernel<<<8192, 256, 0, stream>>>(out, cv, w);
  seq_softmax_kernel<<<8, 256, 0, stream>>>(w);
  scale_kernel<<<8192, 256, 0, stream>>>(out, w);
}

// Round 5
// 592.644 us; speedup vs baseline: 2.4164x; 1.1692x over previous
//
#include <hip/hip_runtime.h>
#include <math.h>
#include <cstddef>
#include <cstdint>

#define B_ 8
#define S_ 4096
#define D_ 256

typedef __attribute__((ext_vector_type(8))) short short8v;   // 8 bf16 (4 VGPR)
typedef __attribute__((ext_vector_type(4))) short short4v;   // 4 bf16 (8 B)
typedef __attribute__((ext_vector_type(4))) float float4v;   // MFMA C/D

// float -> bf16 (RNE) and back, on bit patterns
__device__ __forceinline__ unsigned short f2bf(float f) {
  unsigned u = __float_as_uint(f);
  return (unsigned short)((u + 0x7FFF + ((u >> 16) & 1)) >> 16);
}
__device__ __forceinline__ float bf2f(unsigned short h) {
  return __uint_as_float((unsigned)h << 16);
}
__device__ __forceinline__ unsigned packp(float p) {
  const unsigned short hh = f2bf(p);
  const unsigned short ll = f2bf(p - bf2f(hh));
  return ((unsigned)hh << 16) | (unsigned)ll;
}

// ---------------------------------------------------------------------------
// W pre-split: W[k][n] fp32 -> Wt_h/Wt_l [n][k] bf16 (transposed, split).
// wsp layout: matrix M (0=Wq,1=Wk,2=Wv,3=Wo): h at M*131072 + n*256 + k,
//             l at M*131072 + 65536 + n*256 + k.
// Grid (64): 4 matrices x 16 k-chunks of 16. Coalesced reads, 32B writes.
// ---------------------------------------------------------------------------
__global__ __launch_bounds__(256) void wsplit_kernel(
    const float* __restrict__ Wq, const float* __restrict__ Wk,
    const float* __restrict__ Wv, const float* __restrict__ Wo,
    short* __restrict__ wsp) {
  const int mat = blockIdx.x >> 4;
  const int k0  = (blockIdx.x & 15) << 4;
  const float* W = (mat == 0) ? Wq : (mat == 1) ? Wk : (mat == 2) ? Wv : Wo;
  const int n = threadIdx.x;
  short8v h0, h1, l0, l1;
#pragma unroll
  for (int j = 0; j < 8; ++j) {
    float y = W[(size_t)(k0 + j) * 256 + n];
    unsigned short hh = f2bf(y);
    h0[j] = (short)hh; l0[j] = (short)f2bf(y - bf2f(hh));
    y = W[(size_t)(k0 + 8 + j) * 256 + n];
    hh = f2bf(y);
    h1[j] = (short)hh; l1[j] = (short)f2bf(y - bf2f(hh));
  }
  short* dh = wsp + (size_t)mat * 131072 + (size_t)n * 256 + k0;
  short* dl = dh + 65536;
  *(short8v*)(dh + 0) = h0; *(short8v*)(dh + 8) = h1;
  *(short8v*)(dl + 0) = l0; *(short8v*)(dl + 8) = l1;
}

// ---------------------------------------------------------------------------
// Fused QKV projection, split-bf16 3-term MFMA (frag layouts copied from the
// verified flash kernel):
//   Q,K (p=0,1): SWAPPED  mfma(W_frag, x_frag) -> lane owns s-row = lane&15,
//                n = nt*16 + quad*4 + r  -> 8B short4v stores, [s][d] layout.
//   V   (p=2):   NATURAL  mfma(x_frag, W_frag) -> lane owns d-col = nt*16+m,
//                s = quad*4 + r          -> 8B stores along s, [d][s] layout.
// x is read ONCE (in-register split into xh/xl frags, reused for all 3).
// W slices staged in LDS per kk (pad 40 shorts -> uniform bank quads).
// 512 blocks x 256 thr (4 waves, 64 s-rows/block); 2 blocks/CU.
// ---------------------------------------------------------------------------
__global__ __launch_bounds__(256, 2) void proj_qkv_mfma(
    const float* __restrict__ x, const short* __restrict__ wsp,
    const float* __restrict__ bq, const float* __restrict__ bk,
    const float* __restrict__ bvv,
    short* __restrict__ qh, short* __restrict__ ql,
    short* __restrict__ kh, short* __restrict__ kl,
    short* __restrict__ vth, short* __restrict__ vtl) {
  __shared__ __align__(16) short sWh[256 * 40];  // 20 KB
  __shared__ __align__(16) short sWl[256 * 40];  // 20 KB

  const int t    = threadIdx.x;
  const int w    = t >> 6;
  const int lane = t & 63;
  const int m    = lane & 15;
  const int quad = lane >> 4;
  const size_t r0 = (size_t)blockIdx.x * 64;
  const size_t srow = r0 + 16 * w + m;

  // x-frags, split once, reused by Q/K/V
  short8v xh[8], xl[8];
#pragma unroll
  for (int kk = 0; kk < 8; ++kk) {
    const float* xp = x + srow * 256 + kk * 32 + quad * 8;
    const float4 a = *(const float4*)xp;
    const float4 b2 = *(const float4*)(xp + 4);
    const float v[8] = {a.x, a.y, a.z, a.w, b2.x, b2.y, b2.z, b2.w};
    short8v h, l;
#pragma unroll
    for (int e = 0; e < 8; ++e) {
      const unsigned short hh = f2bf(v[e]);
      h[e] = (short)hh; l[e] = (short)f2bf(v[e] - bf2f(hh));
    }
    xh[kk] = h; xl[kk] = l;
  }

#pragma unroll
  for (int p = 0; p < 3; ++p) {
    const short* wbase = wsp + (size_t)p * 131072;
    float4v acc[16];
#pragma unroll
    for (int nt = 0; nt < 16; ++nt) acc[nt] = (float4v){0.f, 0.f, 0.f, 0.f};

    for (int kk = 0; kk < 8; ++kk) {
      __syncthreads();   // prior MFMA reads of sW done
      {
        const short* gh = wbase + (size_t)t * 256 + kk * 32;
        const short* gl = gh + 65536;
#pragma unroll
        for (int j = 0; j < 4; ++j) {
          *(short8v*)&sWh[t * 40 + j * 8] = *(const short8v*)(gh + j * 8);
          *(short8v*)&sWl[t * 40 + j * 8] = *(const short8v*)(gl + j * 8);
        }
      }
      __syncthreads();   // publish slice
#pragma unroll
      for (int nt = 0; nt < 16; ++nt) {
        const short8v wh = *(const short8v*)&sWh[(nt * 16 + m) * 40 + quad * 8];
        const short8v wl = *(const short8v*)&sWl[(nt * 16 + m) * 40 + quad * 8];
        if (p < 2) {   // swapped: A = W^T rows (n), B = x rows (s cols)
          acc[nt] = __builtin_amdgcn_mfma_f32_16x16x32_bf16(wh, xh[kk], acc[nt], 0, 0, 0);
          acc[nt] = __builtin_amdgcn_mfma_f32_16x16x32_bf16(wh, xl[kk], acc[nt], 0, 0, 0);
          acc[nt] = __builtin_amdgcn_mfma_f32_16x16x32_bf16(wl, xh[kk], acc[nt], 0, 0, 0);
        } else {       // natural: A = x rows (s), B = W cols (d)
          acc[nt] = __builtin_amdgcn_mfma_f32_16x16x32_bf16(xh[kk], wh, acc[nt], 0, 0, 0);
          acc[nt] = __builtin_amdgcn_mfma_f32_16x16x32_bf16(xh[kk], wl, acc[nt], 0, 0, 0);
          acc[nt] = __builtin_amdgcn_mfma_f32_16x16x32_bf16(xl[kk], wh, acc[nt], 0, 0, 0);
        }
      }
    }

    if (p < 2) {
      // swapped C': acc[nt][r] = y[n = nt*16+quad*4+r][s = srow]
      const float scale = (p == 0) ? 0.0625f : 1.0f;
      short* oh = (p == 0) ? qh : kh;
      short* ol = (p == 0) ? ql : kl;
      const float* bias = (p == 0) ? bq : bk;
#pragma unroll
      for (int nt = 0; nt < 16; ++nt) {
        const float4 bb = *(const float4*)(bias + nt * 16 + quad * 4);
        const float bb4[4] = {bb.x, bb.y, bb.z, bb.w};
        short4v h4, l4;
#pragma unroll
        for (int r = 0; r < 4; ++r) {
          const float y = (acc[nt][r] + bb4[r]) * scale;
          const unsigned short hh = f2bf(y);
          h4[r] = (short)hh; l4[r] = (short)f2bf(y - bf2f(hh));
        }
        *(short4v*)(oh + srow * 256 + nt * 16 + quad * 4) = h4;
        *(short4v*)(ol + srow * 256 + nt * 16 + quad * 4) = l4;
      }
    } else {
      // natural C: acc[nt][r] = v[s-local = 16w+quad*4+r][d = nt*16+m]
      const int bidx = (int)(r0 >> 12);
      const size_t bD = (size_t)bidx * (D_ * (size_t)S_);
      const int sl0 = (int)(r0 & 4095) + 16 * w + quad * 4;
#pragma unroll
      for (int nt = 0; nt < 16; ++nt) {
        const int d = nt * 16 + m;
        const float bn = bvv[d];
        short4v h4, l4;
#pragma unroll
        for (int r = 0; r < 4; ++r) {
          const float y = acc[nt][r] + bn;
          const unsigned short hh = f2bf(y);
          h4[r] = (short)hh; l4[r] = (short)f2bf(y - bf2f(hh));
        }
        *(short4v*)(vth + bD + (size_t)d * S_ + sl0) = h4;
        *(short4v*)(vtl + bD + (size_t)d * S_ + sl0) = l4;
      }
    }
  }
}

// ---------------------------------------------------------------------------
// Output GEMM: out = ctx @ Wo + bo (fp32 out), split-bf16 3-term MFMA,
// SWAPPED orientation (lane owns s-row) -> 16B float4 stores; the wdot
// (w[s] = dot(out[s,:], cv)) is fused into the epilogue (saves a 33MB pass).
// ---------------------------------------------------------------------------
__global__ __launch_bounds__(256, 2) void gemm_out_mfma(
    const float* __restrict__ ctx, const short* __restrict__ wsp,
    const float* __restrict__ bo, const float* __restrict__ cv,
    float* __restrict__ out, float* __restrict__ wvec) {
  __shared__ __align__(16) short sWh[256 * 40];
  __shared__ __align__(16) short sWl[256 * 40];

  const int t    = threadIdx.x;
  const int w    = t >> 6;
  const int lane = t & 63;
  const int m    = lane & 15;
  const int quad = lane >> 4;
  const size_t r0 = (size_t)blockIdx.x * 64;
  const size_t srow = r0 + 16 * w + m;
  const short* wbase = wsp + (size_t)3 * 131072;   // Wo

  // ctx-frags, split in-kernel
  short8v ah[8], al[8];
#pragma unroll
  for (int kk = 0; kk < 8; ++kk) {
    const float* xp = ctx + srow * 256 + kk * 32 + quad * 8;
    const float4 a = *(const float4*)xp;
    const float4 b2 = *(const float4*)(xp + 4);
    const float v[8] = {a.x, a.y, a.z, a.w, b2.x, b2.y, b2.z, b2.w};
    short8v h, l;
#pragma unroll
    for (int e = 0; e < 8; ++e) {
      const unsigned short hh = f2bf(v[e]);
      h[e] = (short)hh; l[e] = (short)f2bf(v[e] - bf2f(hh));
    }
    ah[kk] = h; al[kk] = l;
  }

  float4v acc[16];
#pragma unroll
  for (int nt = 0; nt < 16; ++nt) acc[nt] = (float4v){0.f, 0.f, 0.f, 0.f};

  for (int kk = 0; kk < 8; ++kk) {
    __syncthreads();
    {
      const short* gh = wbase + (size_t)t * 256 + kk * 32;
      const short* gl = gh + 65536;
#pragma unroll
      for (int j = 0; j < 4; ++j) {
        *(short8v*)&sWh[t * 40 + j * 8] = *(const short8v*)(gh + j * 8);
        *(short8v*)&sWl[t * 40 + j * 8] = *(const short8v*)(gl + j * 8);
      }
    }
    __syncthreads();
#pragma unroll
    for (int nt = 0; nt < 16; ++nt) {
      const short8v wh = *(const short8v*)&sWh[(nt * 16 + m) * 40 + quad * 8];
      const short8v wl = *(const short8v*)&sWl[(nt * 16 + m) * 40 + quad * 8];
      acc[nt] = __builtin_amdgcn_mfma_f32_16x16x32_bf16(wh, ah[kk], acc[nt], 0, 0, 0);
      acc[nt] = __builtin_amdgcn_mfma_f32_16x16x32_bf16(wh, al[kk], acc[nt], 0, 0, 0);
      acc[nt] = __builtin_amdgcn_mfma_f32_16x16x32_bf16(wl, ah[kk], acc[nt], 0, 0, 0);
    }
  }

  // epilogue: acc[nt][r] = logits[n = nt*16+quad*4+r][s = srow]
  float wp = 0.f;
  float* orow = out + srow * 256;
#pragma unroll
  for (int nt = 0; nt < 16; ++nt) {
    const float4 bb = *(const float4*)(bo + nt * 16 + quad * 4);
    const float4 cc = *(const float4*)(cv + nt * 16 + quad * 4);
    float4 o;
    o.x = acc[nt][0] + bb.x; o.y = acc[nt][1] + bb.y;
    o.z = acc[nt][2] + bb.z; o.w = acc[nt][3] + bb.w;
    wp += o.x * cc.x + o.y * cc.y + o.z * cc.z + o.w * cc.w;
    *(float4*)(orow + nt * 16 + quad * 4) = o;
  }
  wp += __shfl_xor(wp, 16, 64);
  wp += __shfl_xor(wp, 32, 64);
  if (quad == 0) wvec[srow] = wp;
}

// ---------------------------------------------------------------------------
// MFMA flash attention, split-bf16 (3-term) — UNCHANGED from R4 (433 µs).
// ---------------------------------------------------------------------------
__global__ __launch_bounds__(512, 2) void flash_attn_mfma(
    const short* __restrict__ qh, const short* __restrict__ ql,
    const short* __restrict__ kh, const short* __restrict__ kl,
    const short* __restrict__ vth, const short* __restrict__ vtl,
    float* __restrict__ ctx) {
  __shared__ __align__(16) short sK[16896];    // Kh [32 j][264 pad] @0, Kl @8448
  __shared__ __align__(16) short sV[20480];    // Vth [256 d][40 pad] @0, Vtl @10240
  __shared__ unsigned int sP[8][16][36];       // 18 KB, per-wave P tiles (row=q-row)

  const int t    = threadIdx.x;
  const int w    = t >> 6;          // 0..7
  const int lane = t & 63;
  const int m    = lane & 15;
  const int quad = lane >> 4;
  const int q0   = blockIdx.x * 128;
  const int b    = blockIdx.y;
  const size_t sd = (size_t)b * (S_ * (size_t)D_);
  const size_t bD = (size_t)b * (D_ * (size_t)S_);

  short8v aqh[8], aql[8];
  {
    const size_t row = sd + (size_t)(q0 + 16 * w + m) * D_;
#pragma unroll
    for (int kk = 0; kk < 8; ++kk) {
      const size_t off = row + kk * 32 + quad * 8;
      aqh[kk] = *(const short8v*)(qh + off);
      aql[kk] = *(const short8v*)(ql + off);
    }
  }

  short8v ones;
#pragma unroll
  for (int e = 0; e < 8; ++e) ones[e] = (short)0x3F80;

  float4v acc[16];
#pragma unroll
  for (int dt = 0; dt < 16; ++dt) acc[dt] = (float4v){0.f, 0.f, 0.f, 0.f};
  float4v accl = (float4v){0.f, 0.f, 0.f, 0.f};
  float m_i = -INFINITY;

  const int kr0 = t >> 5;
  const int kc0 = (t & 31) << 3;
  const int vd  = t >> 1;
  const int vjh = (t & 1) << 4;

  short8v rKh0, rKh1, rKl0, rKl1;
  short8v rVh0, rVh1, rVl0, rVl1;

  {
    const size_t g0 = sd + (size_t)kr0 * D_ + kc0;
    const size_t g1 = sd + (size_t)(16 + kr0) * D_ + kc0;
    rKh0 = *(const short8v*)(kh + g0);
    rKh1 = *(const short8v*)(kh + g1);
    rKl0 = *(const short8v*)(kl + g0);
    rKl1 = *(const short8v*)(kl + g1);
  }

  for (int jt = 0; jt < 128; ++jt) {
    const int j0 = jt << 5;

    *(short8v*)&sK[kr0 * 264 + kc0]               = rKh0;
    *(short8v*)&sK[(16 + kr0) * 264 + kc0]        = rKh1;
    *(short8v*)&sK[8448 + kr0 * 264 + kc0]        = rKl0;
    *(short8v*)&sK[8448 + (16 + kr0) * 264 + kc0] = rKl1;
    {
      const size_t g = bD + (size_t)vd * S_ + j0 + vjh;
      rVh0 = *(const short8v*)(vth + g);
      rVh1 = *(const short8v*)(vth + g + 8);
      rVl0 = *(const short8v*)(vtl + g);
      rVl1 = *(const short8v*)(vtl + g + 8);
    }
    asm volatile("s_waitcnt lgkmcnt(0)" ::: "memory");
    __builtin_amdgcn_s_barrier();
    asm volatile("" ::: "memory");

    float4v s0 = (float4v){0.f, 0.f, 0.f, 0.f};
    float4v s1 = (float4v){0.f, 0.f, 0.f, 0.f};
    __builtin_amdgcn_s_setprio(1);
#pragma unroll
    for (int kk = 0; kk < 8; ++kk) {
      const int co = kk * 32 + quad * 8;
      const short8v bh0 = *(const short8v*)&sK[m * 264 + co];
      const short8v bl0 = *(const short8v*)&sK[8448 + m * 264 + co];
      const short8v bh1 = *(const short8v*)&sK[(16 + m) * 264 + co];
      const short8v bl1 = *(const short8v*)&sK[8448 + (16 + m) * 264 + co];
      s0 = __builtin_amdgcn_mfma_f32_16x16x32_bf16(bh0, aqh[kk], s0, 0, 0, 0);
      s0 = __builtin_amdgcn_mfma_f32_16x16x32_bf16(bh0, aql[kk], s0, 0, 0, 0);
      s0 = __builtin_amdgcn_mfma_f32_16x16x32_bf16(bl0, aqh[kk], s0, 0, 0, 0);
      s1 = __builtin_amdgcn_mfma_f32_16x16x32_bf16(bh1, aqh[kk], s1, 0, 0, 0);
      s1 = __builtin_amdgcn_mfma_f32_16x16x32_bf16(bh1, aql[kk], s1, 0, 0, 0);
      s1 = __builtin_amdgcn_mfma_f32_16x16x32_bf16(bl1, aqh[kk], s1, 0, 0, 0);
    }
    __builtin_amdgcn_s_setprio(0);

    {
      float mx = fmaxf(fmaxf(fmaxf(s0[0], s0[1]), fmaxf(s0[2], s0[3])),
                       fmaxf(fmaxf(s1[0], s1[1]), fmaxf(s1[2], s1[3])));
      mx = fmaxf(mx, __shfl_xor(mx, 16, 64));
      mx = fmaxf(mx, __shfl_xor(mx, 32, 64));
      if (__any(mx > m_i + 8.0f)) {
        const float mnew = fmaxf(m_i, mx);
        const float alpha = __expf(m_i - mnew);
        m_i = mnew;
        float al[4];
#pragma unroll
        for (int r = 0; r < 4; ++r) al[r] = __shfl(alpha, 20 * quad + r, 64);
#pragma unroll
        for (int dt = 0; dt < 16; ++dt)
#pragma unroll
          for (int r = 0; r < 4; ++r) acc[dt][r] *= al[r];
#pragma unroll
        for (int r = 0; r < 4; ++r) accl[r] *= al[r];
      }
    }

    {
      uint4 w0, w1;
      w0.x = packp(__expf(s0[0] - m_i));
      w0.y = packp(__expf(s0[1] - m_i));
      w0.z = packp(__expf(s0[2] - m_i));
      w0.w = packp(__expf(s0[3] - m_i));
      w1.x = packp(__expf(s1[0] - m_i));
      w1.y = packp(__expf(s1[1] - m_i));
      w1.z = packp(__expf(s1[2] - m_i));
      w1.w = packp(__expf(s1[3] - m_i));
      *(uint4*)&sP[w][m][4 * quad]      = w0;
      *(uint4*)&sP[w][m][16 + 4 * quad] = w1;
    }

    *(short8v*)&sV[vd * 40 + vjh]               = rVh0;
    *(short8v*)&sV[vd * 40 + vjh + 8]           = rVh1;
    *(short8v*)&sV[10240 + vd * 40 + vjh]       = rVl0;
    *(short8v*)&sV[10240 + vd * 40 + vjh + 8]   = rVl1;
    if (jt < 127) {
      const int j0n = j0 + 32;
      const size_t g0 = sd + (size_t)(j0n + kr0) * D_ + kc0;
      const size_t g1 = sd + (size_t)(j0n + 16 + kr0) * D_ + kc0;
      rKh0 = *(const short8v*)(kh + g0);
      rKh1 = *(const short8v*)(kh + g1);
      rKl0 = *(const short8v*)(kl + g0);
      rKl1 = *(const short8v*)(kl + g1);
    }
    asm volatile("s_waitcnt lgkmcnt(0)" ::: "memory");
    __builtin_amdgcn_s_barrier();
    asm volatile("" ::: "memory");

    short8v ph, pl;
    {
      const uint4 pa = *(const uint4*)&sP[w][m][quad * 8];
      const uint4 pb = *(const uint4*)&sP[w][m][quad * 8 + 4];
      ph[0] = (short)(pa.x >> 16); pl[0] = (short)(pa.x & 0xffff);
      ph[1] = (short)(pa.y >> 16); pl[1] = (short)(pa.y & 0xffff);
      ph[2] = (short)(pa.z >> 16); pl[2] = (short)(pa.z & 0xffff);
      ph[3] = (short)(pa.w >> 16); pl[3] = (short)(pa.w & 0xffff);
      ph[4] = (short)(pb.x >> 16); pl[4] = (short)(pb.x & 0xffff);
      ph[5] = (short)(pb.y >> 16); pl[5] = (short)(pb.y & 0xffff);
      ph[6] = (short)(pb.z >> 16); pl[6] = (short)(pb.z & 0xffff);
      ph[7] = (short)(pb.w >> 16); pl[7] = (short)(pb.w & 0xffff);
    }

    __builtin_amdgcn_s_setprio(1);
    accl = __builtin_amdgcn_mfma_f32_16x16x32_bf16(ph, ones, accl, 0, 0, 0);
    accl = __builtin_amdgcn_mfma_f32_16x16x32_bf16(pl, ones, accl, 0, 0, 0);
#pragma unroll
    for (int dt = 0; dt < 16; ++dt) {
      const int vr = (dt * 16 + m) * 40 + quad * 8;
      const short8v bh = *(const short8v*)&sV[vr];
      const short8v bl = *(const short8v*)&sV[10240 + vr];
      acc[dt] = __builtin_amdgcn_mfma_f32_16x16x32_bf16(ph, bh, acc[dt], 0, 0, 0);
      acc[dt] = __builtin_amdgcn_mfma_f32_16x16x32_bf16(ph, bl, acc[dt], 0, 0, 0);
      acc[dt] = __builtin_amdgcn_mfma_f32_16x16x32_bf16(pl, bh, acc[dt], 0, 0, 0);
    }
    __builtin_amdgcn_s_setprio(0);
  }

#pragma unroll
  for (int r = 0; r < 4; ++r) {
    const float inv = 1.0f / accl[r];
    float* cp = ctx + sd + (size_t)(q0 + 16 * w + quad * 4 + r) * D_ + m;
#pragma unroll
    for (int dt = 0; dt < 16; ++dt) cp[dt * 16] = acc[dt][r] * inv;
  }
}

// ---------------------------------------------------------------------------
// softmax over sequence dim per batch (in place on w)
// ---------------------------------------------------------------------------
__global__ __launch_bounds__(256) void seq_softmax_kernel(float* __restrict__ w) {
  __shared__ float red[4];
  const int b = blockIdx.x, t = threadIdx.x;
  const int wave = t >> 6, lane = t & 63;
  float* wb = w + (size_t)b * S_;
  float vals[16];
  float mx = -INFINITY;
#pragma unroll
  for (int i = 0; i < 16; ++i) {
    vals[i] = wb[t + (i << 8)];
    mx = fmaxf(mx, vals[i]);
  }
#pragma unroll
  for (int off = 32; off > 0; off >>= 1) mx = fmaxf(mx, __shfl_xor(mx, off, 64));
  if (lane == 0) red[wave] = mx;
  __syncthreads();
  const float M = fmaxf(fmaxf(red[0], red[1]), fmaxf(red[2], red[3]));
  float sum = 0.f;
#pragma unroll
  for (int i = 0; i < 16; ++i) {
    vals[i] = __expf(vals[i] - M);
    sum += vals[i];
  }
#pragma unroll
  for (int off = 32; off > 0; off >>= 1) sum += __shfl_xor(sum, off, 64);
  __syncthreads();
  if (lane == 0) red[wave] = sum;
  __syncthreads();
  const float inv = 1.0f / (red[0] + red[1] + red[2] + red[3]);
#pragma unroll
  for (int i = 0; i < 16; ++i) wb[t + (i << 8)] = vals[i] * inv;
}

// ---------------------------------------------------------------------------
// out[b,s,:] *= nw[b,s]
// ---------------------------------------------------------------------------
__global__ __launch_bounds__(256) void scale_kernel(
    float* __restrict__ out, const float* __restrict__ nw) {
  const size_t g = (size_t)blockIdx.x * 256 + threadIdx.x;
  float4* o4 = (float4*)out;
  float4 vv = o4[g];
  const float sc = nw[g >> 6];
  vv.x *= sc; vv.y *= sc; vv.z *= sc; vv.w *= sc;
  o4[g] = vv;
}

// ---------------------------------------------------------------------------
extern "C" void kernel_launch(void* const* d_in, const int* in_sizes, int n_in,
                              void* d_out, int out_size, void* d_ws, size_t ws_size,
                              hipStream_t stream) {
  const float* x  = (const float*)d_in[0];
  const float* Wq = (const float*)d_in[1];
  const float* bq = (const float*)d_in[2];
  const float* Wk = (const float*)d_in[3];
  const float* bk = (const float*)d_in[4];
  const float* Wv = (const float*)d_in[5];
  const float* bv = (const float*)d_in[6];
  const float* Wo = (const float*)d_in[7];
  const float* bo = (const float*)d_in[8];
  const float* cv = (const float*)d_in[9];
  float* out = (float*)d_out;

  const size_t N = (size_t)B_ * S_ * D_;  // 8,388,608 elements
  short* qh  = (short*)d_ws;      // [b][s][d] bf16 hi (Q pre-scaled by 1/16)
  short* ql  = qh + N;            // [b][s][d] bf16 lo
  short* kh  = ql + N;            // [b][s][d]
  short* kl  = kh + N;
  short* vth = kl + N;            // [b][d][s]
  short* vtl = vth + N;
  float* ctx = (float*)(vtl + N); // [b][s][d] fp32
  float* w   = ctx + N;           // B*S floats
  short* wsp = (short*)(w + (size_t)B_ * S_);  // 4 x 131072 shorts (1 MB)

  wsplit_kernel<<<64, 256, 0, stream>>>(Wq, Wk, Wv, Wo, wsp);
  proj_qkv_mfma<<<512, 256, 0, stream>>>(x, wsp, bq, bk, bv,
                                         qh, ql, kh, kl, vth, vtl);
  flash_attn_mfma<<<dim3(32, 8), 512, 0, stream>>>(qh, ql, kh, kl, vth, vtl, ctx);
  gemm_out_mfma<<<512, 256, 0, stream>>>(ctx, wsp, bo, cv, out, w);
  seq_softmax_kernel<<<8, 256, 0, stream>>>(w);
  scale_kernel<<<8192, 256, 0, stream>>>(out, w);
}